// Round 1
// baseline (1366.117 us; speedup 1.0000x reference)
//
#include <hip/hip_runtime.h>

// PrecisionGatedMoE: B=8192, H=4096, E=8, fp32.
// One block per row b. Phase 1: gate dot (fp64 accum for selection fidelity),
// Phase 2: streaming top-2 weighted combine. HBM-bound: ideal ~537 MB traffic.

constexpr int H = 4096;
constexpr int E = 8;
constexpr int BLOCK = 256;  // multiple of wave=64

__global__ __launch_bounds__(BLOCK) void moe_fused_kernel(
    const float* __restrict__ hidden,   // B x H
    const float* __restrict__ expert,   // E x B x H
    const float* __restrict__ gate_w,   // H x E
    const float* __restrict__ gate_b,   // E
    float* __restrict__ out,            // B x H
    int B)
{
    const int b = blockIdx.x;
    const int t = threadIdx.x;

    // ---------------- Phase 1: gate scores ----------------
    // Each thread processes H/BLOCK = 16 elements as 4 float4 loads.
    const float4* hrow4 = (const float4*)(hidden + (size_t)b * H);

    double acc[E];
#pragma unroll
    for (int e = 0; e < E; ++e) acc[e] = 0.0;

#pragma unroll
    for (int i = 0; i < H / 4 / BLOCK; ++i) {   // 4 iterations
        const int h4 = t + i * BLOCK;           // float4 index
        const float4 x = hrow4[h4];
        // gate_w rows for elements 4*h4 .. 4*h4+3 : 8 float4s, contiguous 128B
        const float4* gw = (const float4*)(gate_w + (size_t)(4 * h4) * E);
        const float xs[4] = {x.x, x.y, x.z, x.w};
#pragma unroll
        for (int j = 0; j < 4; ++j) {
            const float4 g0 = gw[2 * j + 0];
            const float4 g1 = gw[2 * j + 1];
            acc[0] += (double)xs[j] * (double)g0.x;
            acc[1] += (double)xs[j] * (double)g0.y;
            acc[2] += (double)xs[j] * (double)g0.z;
            acc[3] += (double)xs[j] * (double)g0.w;
            acc[4] += (double)xs[j] * (double)g1.x;
            acc[5] += (double)xs[j] * (double)g1.y;
            acc[6] += (double)xs[j] * (double)g1.z;
            acc[7] += (double)xs[j] * (double)g1.w;
        }
    }

    // Wave-level butterfly reduction (64 lanes).
#pragma unroll
    for (int e = 0; e < E; ++e) {
        double v = acc[e];
#pragma unroll
        for (int off = 32; off > 0; off >>= 1)
            v += __shfl_xor(v, off, 64);
        acc[e] = v;
    }

    __shared__ double s_acc[BLOCK / 64][E];
    __shared__ int   s_i0, s_i1;
    __shared__ float s_w0, s_w1;

    const int wave = t >> 6;
    const int lane = t & 63;
    if (lane == 0) {
#pragma unroll
        for (int e = 0; e < E; ++e) s_acc[wave][e] = acc[e];
    }
    __syncthreads();

    if (t == 0) {
        double s[E];
#pragma unroll
        for (int e = 0; e < E; ++e) {
            double v = (double)gate_b[e];
#pragma unroll
            for (int w = 0; w < BLOCK / 64; ++w) v += s_acc[w][e];
            s[e] = v;
        }
        // top-2 with lowest-index tie-break (matches jax.lax.top_k)
        int i0 = 0;
#pragma unroll
        for (int e = 1; e < E; ++e) if (s[e] > s[i0]) i0 = e;
        int i1 = (i0 == 0) ? 1 : 0;
#pragma unroll
        for (int e = 0; e < E; ++e) {
            if (e == i0) continue;
            if (s[e] > s[i1]) i1 = e;
        }
        // softmax over {s[i0], s[i1]} renormalized: w0 = 1/(1+exp(s1-s0))
        const double d = s[i1] - s[i0];    // <= 0
        const double w0 = 1.0 / (1.0 + exp(d));
        s_i0 = i0; s_i1 = i1;
        s_w0 = (float)w0;
        s_w1 = (float)(1.0 - w0);
    }
    __syncthreads();

    // ---------------- Phase 2: weighted combine ----------------
    const int   i0 = s_i0, i1 = s_i1;
    const float w0 = s_w0, w1 = s_w1;
    const float4* e0 = (const float4*)(expert + ((size_t)i0 * B + b) * H);
    const float4* e1 = (const float4*)(expert + ((size_t)i1 * B + b) * H);
    float4* o = (float4*)(out + (size_t)b * H);

#pragma unroll
    for (int i = 0; i < H / 4 / BLOCK; ++i) {   // 4 iterations
        const int idx = t + i * BLOCK;
        const float4 a = e0[idx];
        const float4 c = e1[idx];
        float4 r;
        r.x = w0 * a.x + w1 * c.x;
        r.y = w0 * a.y + w1 * c.y;
        r.z = w0 * a.z + w1 * c.z;
        r.w = w0 * a.w + w1 * c.w;
        o[idx] = r;
    }
}

extern "C" void kernel_launch(void* const* d_in, const int* in_sizes, int n_in,
                              void* d_out, int out_size, void* d_ws, size_t ws_size,
                              hipStream_t stream) {
    const float* hidden = (const float*)d_in[0];
    const float* expert = (const float*)d_in[1];
    const float* gate_w = (const float*)d_in[2];
    const float* gate_b = (const float*)d_in[3];
    float* out = (float*)d_out;

    const int B = in_sizes[0] / H;   // 8192

    moe_fused_kernel<<<B, BLOCK, 0, stream>>>(hidden, expert, gate_w, gate_b, out, B);
}